// Round 5
// baseline (639.957 us; speedup 1.0000x reference)
//
#include <hip/hip_runtime.h>

#define DEVI __device__ __forceinline__

typedef __attribute__((ext_vector_type(8))) __bf16 bf16x8;
typedef __attribute__((ext_vector_type(16))) float floatx16;

constexpr int Bsz = 8192;   // batch
constexpr int Hd  = 2048;   // hidden
constexpr int INd = 2048;   // input dim
constexpr int N1  = Bsz * INd;

DEVI unsigned short f2bf_rne(float f) {
  unsigned int u = __float_as_uint(f);
  u += 0x7FFFu + ((u >> 16) & 1u);
  return (unsigned short)(u >> 16);
}

__global__ void cvt4(const float* __restrict__ s0, const float* __restrict__ s1,
                     const float* __restrict__ s2, const float* __restrict__ s3,
                     unsigned short* __restrict__ dst) {
  const float* src = (blockIdx.y == 0) ? s0 : (blockIdx.y == 1) ? s1
                   : (blockIdx.y == 2) ? s2 : s3;
  unsigned short* out = dst + (size_t)blockIdx.y * N1;
  const int nv = N1 / 4;
  for (int i = blockIdx.x * blockDim.x + threadIdx.x; i < nv;
       i += gridDim.x * blockDim.x) {
    float4 v = ((const float4*)src)[i];
    ushort4 o;
    o.x = f2bf_rne(v.x); o.y = f2bf_rne(v.y);
    o.z = f2bf_rne(v.z); o.w = f2bf_rne(v.w);
    ((ushort4*)out)[i] = o;
  }
}

DEVI void gload_lds16(const void* g, void* l) {
  __builtin_amdgcn_global_load_lds(
      (const __attribute__((address_space(1))) void*)g,
      (__attribute__((address_space(3))) void*)l, 16, 0, 0);
}

DEVI float sigm(float x) { return 1.0f / (1.0f + __expf(-x)); }

// 256(batch) x 256(weight) tile, BK=64, 8 waves (2 weight-M x 4 batch-N),
// 32x32x16 MFMA, TRANSPOSED: mfma(W_frag, X_frag) so weight dim is the
// reg-indexed C dim. Weight-row layout wr = whi*32 + gate*8 + wlo makes
// gate = reg>>2 (lane-local epilogue, float4 stores). 4 phases/K-tile over
// quadrant ring (0,0)->(0,1)->(1,1)->(1,0) with register holds; single
// closing barrier per phase; compiler does counted-lgkm interleave.
__global__ __launch_bounds__(512, 2) void lstm_gemm(
    const unsigned short* __restrict__ ws,
    const float* __restrict__ bias,
    const float* __restrict__ c_prev,
    float* __restrict__ out_h,
    float* __restrict__ out_c) {
  __shared__ __align__(16) unsigned short sm[4 * 256 * 64];  // 128 KiB
  char* smc = (char*)sm;

  const unsigned short* xb  = ws;
  const unsigned short* hb  = ws + (size_t)N1;
  const unsigned short* wih = ws + (size_t)2 * N1;
  const unsigned short* whh = ws + (size_t)3 * N1;

  const int tid  = threadIdx.x;
  const int lane = tid & 63;
  const int wid  = tid >> 6;
  const int ww   = wid >> 2;    // weight-M wave 0..1
  const int wb   = wid & 3;     // batch-N wave 0..3
  const int l31  = lane & 31, l5 = lane >> 5;
  const int lr8  = lane >> 3;
  const int swc  = ((lane & 7) ^ lr8) * 8;   // swizzled source chunk (elems)

  // XCD-aware chunked swizzle (kept from R4: FETCH 1.1GB -> 427MB).
  const int wg = blockIdx.x;
  const int x8 = wg & 7;
  const int lc = wg >> 3;
  const int bc = (x8 & 3) * 8 + (lc & 7);             // h-col tile 0..31
  const int rb = ((x8 >> 2) * 16 + (lc >> 3)) * 256;  // batch row base

  // Per-thread stage source offsets (elements), K-tile-independent.
  unsigned int aOff[2][2], bOff[2][2];
#pragma unroll
  for (int h = 0; h < 2; ++h)
#pragma unroll
    for (int j = 0; j < 2; ++j) {
      const int arow = rb + h * 128 + j * 64 + wid * 8 + lr8;
      aOff[h][j] = (unsigned)arow * 2048u + (unsigned)swc;
      const int wr = h * 128 + j * 64 + wid * 8 + lr8;  // weight-LDS row
      const int wrow = ((wr >> 3) & 3) * 2048 + bc * 64 + (wr >> 5) * 8 + (wr & 7);
      bOff[h][j] = (unsigned)wrow * 2048u + (unsigned)swc;
    }

  floatx16 acc[2][2][2];  // [Qw][mrw][Qb]
#pragma unroll
  for (int a = 0; a < 2; ++a)
#pragma unroll
    for (int b = 0; b < 2; ++b)
#pragma unroll
      for (int c = 0; c < 2; ++c)
#pragma unroll
        for (int e = 0; e < 16; ++e) acc[a][b][c][e] = 0.f;

#define STAGE_A(ts, h) {                                                      \
    const int bs_ = (ts) & 1;                                                 \
    const unsigned short* s_ = (((ts) < 32) ? xb : hb) + (((ts) & 31) * 64);  \
    gload_lds16(s_ + aOff[h][0], smc + bs_ * 32768 + ((h) * 128 + wid * 8) * 128);        \
    gload_lds16(s_ + aOff[h][1], smc + bs_ * 32768 + ((h) * 128 + 64 + wid * 8) * 128); }
#define STAGE_B(ts, h) {                                                      \
    const int bs_ = (ts) & 1;                                                 \
    const unsigned short* s_ = (((ts) < 32) ? wih : whh) + (((ts) & 31) * 64);\
    gload_lds16(s_ + bOff[h][0], smc + 65536 + bs_ * 32768 + ((h) * 128 + wid * 8) * 128);        \
    gload_lds16(s_ + bOff[h][1], smc + 65536 + bs_ * 32768 + ((h) * 128 + 64 + wid * 8) * 128); }

#define LDW(DST, QW)                                                          \
  _Pragma("unroll") for (int mrw = 0; mrw < 2; ++mrw)                         \
    _Pragma("unroll") for (int ks = 0; ks < 4; ++ks) {                        \
      const int row  = (QW) * 128 + ww * 64 + mrw * 32 + l31;                 \
      const int phys = (ks * 2 + l5) ^ (row & 7);                             \
      DST[mrw][ks] = *(const bf16x8*)(Bb + row * 128 + phys * 16); }
#define LDX(DST, QB)                                                          \
  _Pragma("unroll") for (int ks = 0; ks < 4; ++ks) {                          \
      const int row  = (QB) * 128 + wb * 32 + l31;                            \
      const int phys = (ks * 2 + l5) ^ (row & 7);                             \
      DST[ks] = *(const bf16x8*)(Ab + row * 128 + phys * 16); }
#define MM(QW, QB, WF, XF)                                                    \
  __builtin_amdgcn_s_setprio(1);                                              \
  _Pragma("unroll") for (int mrw = 0; mrw < 2; ++mrw)                         \
    _Pragma("unroll") for (int ks = 0; ks < 4; ++ks)                          \
      acc[QW][mrw][QB] = __builtin_amdgcn_mfma_f32_32x32x16_bf16(             \
          WF[mrw][ks], XF[ks], acc[QW][mrw][QB], 0, 0, 0);                    \
  __builtin_amdgcn_s_setprio(0);
#define BAR  asm volatile("s_barrier" ::: "memory")
#define VM4  asm volatile("s_waitcnt vmcnt(4)" ::: "memory")
#define VM0  asm volatile("s_waitcnt vmcnt(0)" ::: "memory")
#define NOP  (void)0

// Phases: (Qw,Qb) = (0,0) (0,1) (1,1) (1,0). Holds: wf over ph1-2 and ph3-4,
// xf1 over ph2-3; xf0 re-read ph4. Stage slots (hazard-safe, t+1 before t+2
// in issue order so vmcnt(4) proves tile t+1 staged):
//   ph1: A(t+1,0)   ph2: B(t+1,1), B(t+2,0)   ph3: A(t+2,1)   ph4: wait
#define KTILE(BETA, S1, S2a, S2b, S3, W4) {                                   \
    const char* Ab = smc + (BETA) * 32768;                                    \
    const char* Bb = smc + 65536 + (BETA) * 32768;                            \
    bf16x8 wf[2][4], xf0[4], xf1[4];                                          \
    LDW(wf, 0); LDX(xf0, 0); S1;                                              \
    MM(0, 0, wf, xf0); BAR;                                                   \
    LDX(xf1, 1); S2a; S2b;                                                    \
    MM(0, 1, wf, xf1); BAR;                                                   \
    LDW(wf, 1); S3;                                                           \
    MM(1, 1, wf, xf1); BAR;                                                   \
    LDX(xf0, 0);                                                              \
    MM(1, 0, wf, xf0); W4; BAR;                                               \
  }

  // Prologue: tile 0 complete in first 8 gloads, then tile 1's (B0,A1) pair.
  STAGE_A(0, 0); STAGE_A(0, 1); STAGE_B(0, 0); STAGE_B(0, 1);
  STAGE_B(1, 0); STAGE_A(1, 1);
  VM4;
  BAR;

  for (int t = 0; t < 62; ++t) {
    KTILE(t & 1, STAGE_A(t + 1, 0), STAGE_B(t + 1, 1),
          STAGE_B(t + 2, 0), STAGE_A(t + 2, 1), VM4);
  }
  KTILE(0, STAGE_A(63, 0), STAGE_B(63, 1), NOP, NOP, VM0);  // t = 62
  KTILE(1, NOP, NOP, NOP, NOP, NOP);                        // t = 63

  // Epilogue: gate = reg>>2 (lane-local), 4 consecutive hcols per reg group
  // -> float4 loads/stores.
#pragma unroll
  for (int qw = 0; qw < 2; ++qw)
#pragma unroll
    for (int mrw = 0; mrw < 2; ++mrw) {
      const int hb4 = bc * 64 + (qw * 4 + ww * 2 + mrw) * 8 + l5 * 4;
      const float4 bi4 = *(const float4*)&bias[hb4];
      const float4 bf4 = *(const float4*)&bias[2048 + hb4];
      const float4 bj4 = *(const float4*)&bias[4096 + hb4];
      const float4 bo4 = *(const float4*)&bias[6144 + hb4];
#pragma unroll
      for (int qb = 0; qb < 2; ++qb) {
        const int brow = rb + qb * 128 + wb * 32 + l31;
        const size_t base = (size_t)brow * 2048 + hb4;
        const float4 cp = *(const float4*)&c_prev[base];
        float4 hv, cv;
#pragma unroll
        for (int q = 0; q < 4; ++q) {
          const float gi = acc[qw][mrw][qb][q]      + ((const float*)&bi4)[q];
          const float gf = acc[qw][mrw][qb][4 + q]  + ((const float*)&bf4)[q];
          const float gj = acc[qw][mrw][qb][8 + q]  + ((const float*)&bj4)[q];
          const float go = acc[qw][mrw][qb][12 + q] + ((const float*)&bo4)[q];
          const float iv = sigm(gi);
          const float fv = sigm(gf);
          const float jv = tanhf(gj);
          const float ov = sigm(go);
          const float cq = fv * ((const float*)&cp)[q] + fminf(1.0f - fv, iv) * jv;
          ((float*)&cv)[q] = cq;
          ((float*)&hv)[q] = ov * tanhf(cq);
        }
        *(float4*)&out_h[base] = hv;
        *(float4*)&out_c[base] = cv;
      }
    }
}

extern "C" void kernel_launch(void* const* d_in, const int* in_sizes, int n_in,
                              void* d_out, int out_size, void* d_ws, size_t ws_size,
                              hipStream_t stream) {
  const float* x      = (const float*)d_in[0];
  const float* h_prev = (const float*)d_in[1];
  const float* c_prev = (const float*)d_in[2];
  const float* w_ih   = (const float*)d_in[3];
  const float* w_hh   = (const float*)d_in[4];
  const float* bias   = (const float*)d_in[5];

  float* out_h = (float*)d_out;
  float* out_c = out_h + (size_t)Bsz * Hd;
  unsigned short* wsb = (unsigned short*)d_ws;

  dim3 cgrid(2048, 4);
  cvt4<<<cgrid, 256, 0, stream>>>(x, h_prev, w_ih, w_hh, wsb);

  lstm_gemm<<<1024, 512, 0, stream>>>(wsb, bias, c_prev, out_h, out_c);
}

// Round 6
// 585.149 us; speedup vs baseline: 1.0937x; 1.0937x over previous
//
#include <hip/hip_runtime.h>

#define DEVI __device__ __forceinline__

typedef __attribute__((ext_vector_type(8))) __bf16 bf16x8;
typedef __attribute__((ext_vector_type(4))) float floatx4;

constexpr int Bsz = 8192;   // batch
constexpr int Hd  = 2048;   // hidden
constexpr int INd = 2048;   // input dim
constexpr int N1  = Bsz * INd;

DEVI unsigned short f2bf_rne(float f) {
  unsigned int u = __float_as_uint(f);
  u += 0x7FFFu + ((u >> 16) & 1u);
  return (unsigned short)(u >> 16);
}

__global__ void cvt4(const float* __restrict__ s0, const float* __restrict__ s1,
                     const float* __restrict__ s2, const float* __restrict__ s3,
                     unsigned short* __restrict__ dst) {
  const float* src = (blockIdx.y == 0) ? s0 : (blockIdx.y == 1) ? s1
                   : (blockIdx.y == 2) ? s2 : s3;
  unsigned short* out = dst + (size_t)blockIdx.y * N1;
  const int nv = N1 / 4;
  for (int i = blockIdx.x * blockDim.x + threadIdx.x; i < nv;
       i += gridDim.x * blockDim.x) {
    float4 v = ((const float4*)src)[i];
    ushort4 o;
    o.x = f2bf_rne(v.x); o.y = f2bf_rne(v.y);
    o.z = f2bf_rne(v.z); o.w = f2bf_rne(v.w);
    ((ushort4*)out)[i] = o;
  }
}

DEVI void gload_lds16(const void* g, void* l) {
  __builtin_amdgcn_global_load_lds(
      (const __attribute__((address_space(1))) void*)g,
      (__attribute__((address_space(3))) void*)l, 16, 0, 0);
}

DEVI float sigm(float x) { return 1.0f / (1.0f + __expf(-x)); }

// 256x256 tile, BK=64, 8 waves (2M x 4N), 16x16x32 MFMA (R4 base, 0-conflict
// swizzle). Ring (0,0)->(1,0)->(1,1)->(0,1) with FULL register holds:
// A0 held ph1..ph4, A1 ph2..ph3, B0 ph1..ph2, B1 ph3..ph4.
// ds_read_b128/wave/K-tile: 24 (unique minimum; was 32) -> LDS cap 89%.
// Phase 4 is read-free (vmcnt wait + pure MFMA window).
__global__ __launch_bounds__(512, 2) void lstm_gemm(
    const unsigned short* __restrict__ ws,
    const float* __restrict__ bias,
    const float* __restrict__ c_prev,
    float* __restrict__ out_h,
    float* __restrict__ out_c) {
  __shared__ __align__(16) unsigned short sm[4 * 256 * 64];  // 128 KiB
  char* smc = (char*)sm;

  const unsigned short* xb  = ws;
  const unsigned short* hb  = ws + (size_t)N1;
  const unsigned short* wih = ws + (size_t)2 * N1;
  const unsigned short* whh = ws + (size_t)3 * N1;

  const int tid  = threadIdx.x;
  const int lane = tid & 63;
  const int wid  = tid >> 6;
  const int wm   = wid >> 2, wn = wid & 3;
  const int lr   = lane & 15, lk = lane >> 4;
  const int lr8  = lane >> 3;
  const int swc  = ((lane & 7) ^ lr8) * 8;   // swizzled source chunk (elems)

  // XCD-aware chunked swizzle (R4: FETCH 1.1GB -> 427MB).
  const int wg = blockIdx.x;
  const int x8 = wg & 7;
  const int lc = wg >> 3;
  const int bc = (x8 & 3) * 8 + (lc & 7);             // h-col tile 0..31
  const int rb = ((x8 >> 2) * 16 + (lc >> 3)) * 256;  // batch row base

  // Per-thread stage source offsets (elements), K-tile-independent.
  unsigned int aOff[2][2], bOff[2][2];
#pragma unroll
  for (int h = 0; h < 2; ++h)
#pragma unroll
    for (int j = 0; j < 2; ++j) {
      const int arow = rb + h * 128 + j * 64 + wid * 8 + lr8;
      aOff[h][j] = (unsigned)arow * 2048u + (unsigned)swc;
      const int c  = h * 128 + j * 64 + wid * 8 + lr8;   // block-col index
      const int cf = c >> 4, ce = c & 15;
      const int gate = (cf & 1) | ((cf >> 2) & 2);
      const int hch  = (cf >> 1) & 3;
      const int brow = gate * 2048 + bc * 64 + hch * 16 + ce;
      bOff[h][j] = (unsigned)brow * 2048u + (unsigned)swc;
    }

  floatx4 acc[2][4][2][2];
#pragma unroll
  for (int a = 0; a < 2; ++a)
#pragma unroll
    for (int b = 0; b < 4; ++b)
#pragma unroll
      for (int c = 0; c < 2; ++c)
#pragma unroll
        for (int d = 0; d < 2; ++d)
          acc[a][b][c][d] = (floatx4){0.f, 0.f, 0.f, 0.f};

#define STAGE_A(ts, h) {                                                      \
    const int bs_ = (ts) & 1;                                                 \
    const unsigned short* s_ = (((ts) < 32) ? xb : hb) + (((ts) & 31) * 64);  \
    gload_lds16(s_ + aOff[h][0], smc + bs_ * 32768 + ((h) * 128 + wid * 8) * 128);        \
    gload_lds16(s_ + aOff[h][1], smc + bs_ * 32768 + ((h) * 128 + 64 + wid * 8) * 128); }
#define STAGE_B(ts, h) {                                                      \
    const int bs_ = (ts) & 1;                                                 \
    const unsigned short* s_ = (((ts) < 32) ? wih : whh) + (((ts) & 31) * 64);\
    gload_lds16(s_ + bOff[h][0], smc + 65536 + bs_ * 32768 + ((h) * 128 + wid * 8) * 128);        \
    gload_lds16(s_ + bOff[h][1], smc + 65536 + bs_ * 32768 + ((h) * 128 + 64 + wid * 8) * 128); }

#define LDA(DST, QM)                                                          \
  _Pragma("unroll") for (int mr = 0; mr < 4; ++mr)                            \
    _Pragma("unroll") for (int s = 0; s < 2; ++s) {                           \
      const int row  = (QM) * 128 + wm * 64 + mr * 16 + lr;                   \
      const int phys = (s * 4 + lk) ^ (row & 7);                              \
      DST[mr][s] = *(const bf16x8*)(Ab + row * 128 + phys * 16); }
#define LDB(DST, QN)                                                          \
  _Pragma("unroll") for (int nc = 0; nc < 2; ++nc)                            \
    _Pragma("unroll") for (int s = 0; s < 2; ++s) {                           \
      const int row  = ((QN) * 8 + wn * 2 + nc) * 16 + lr;                    \
      const int phys = (s * 4 + lk) ^ (row & 7);                              \
      DST[nc][s] = *(const bf16x8*)(Bb + row * 128 + phys * 16); }
#define MFMA16(QM, QN, AF, BG)                                                \
  __builtin_amdgcn_s_setprio(1);                                              \
  _Pragma("unroll") for (int mr = 0; mr < 4; ++mr)                            \
    _Pragma("unroll") for (int nc = 0; nc < 2; ++nc)                          \
      _Pragma("unroll") for (int s = 0; s < 2; ++s)                           \
        acc[QM][mr][QN][nc] = __builtin_amdgcn_mfma_f32_16x16x32_bf16(        \
            AF[mr][s], BG[nc][s], acc[QM][mr][QN][nc], 0, 0, 0);              \
  __builtin_amdgcn_s_setprio(0);
#define BAR  asm volatile("s_barrier" ::: "memory")
#define LGK0 do { asm volatile("s_waitcnt lgkmcnt(0)" ::: "memory");          \
                  __builtin_amdgcn_sched_barrier(0); } while (0)
#define VM4  asm volatile("s_waitcnt vmcnt(4)" ::: "memory")
#define VM0  asm volatile("s_waitcnt vmcnt(0)" ::: "memory")
#define NOP  (void)0

// One K-tile = 4 phases, ring (0,0)(1,0)(1,1)(0,1).
// Reads: ph1 A0(8)+B0(4), ph2 A1(8), ph3 B1(4), ph4 none. Holds per header.
// Stage slots: ph1 A(t+1,0); ph2 B(t+1,1), B(t+2,0); ph3 A(t+2,1); ph4 vmcnt.
// Hazards: each t+2-stage issues >=1 full barrier after its half's last read;
// t+1 loads issue before t+2 loads so vmcnt(4) proves tile t+1 staged.
#define KTILE(BETA, S1, S2a, S2b, S3, W4) {                                   \
    const char* Ab = smc + (BETA) * 32768;                                    \
    const char* Bb = smc + 65536 + (BETA) * 32768;                            \
    bf16x8 afA[4][2], afB[4][2], bg0[2][2], bg1[2][2];                        \
    LDA(afA, 0); LDB(bg0, 0); S1;                                             \
    asm volatile("s_waitcnt lgkmcnt(8)" ::: "memory");                        \
    BAR; LGK0; MFMA16(0, 0, afA, bg0); BAR;                                   \
    LDA(afB, 1); S2a; S2b;                                                    \
    BAR; LGK0; MFMA16(1, 0, afB, bg0); BAR;                                   \
    LDB(bg1, 1); S3;                                                          \
    BAR; LGK0; MFMA16(1, 1, afB, bg1); BAR;                                   \
    W4;                                                                       \
    BAR; MFMA16(0, 1, afA, bg1); BAR;                                         \
  }

  // Prologue: tile 0 complete (8 gloads) + tile 1's (B0,A1) pair; counted drain.
  STAGE_B(0, 0); STAGE_A(0, 1); STAGE_B(0, 1);
  STAGE_A(0, 0); STAGE_B(1, 0); STAGE_A(1, 1);
  VM4;
  BAR;

  for (int t = 0; t < 62; ++t) {
    KTILE(t & 1, STAGE_A(t + 1, 0), STAGE_B(t + 1, 1),
          STAGE_B(t + 2, 0), STAGE_A(t + 2, 1), VM4);
  }
  KTILE(0, STAGE_A(63, 0), STAGE_B(63, 1), NOP, NOP, VM0);  // t = 62
  KTILE(1, NOP, NOP, NOP, NOP, NOP);                        // t = 63

  // Epilogue: lane-local LSTM (all 4 gates live in-lane).
  const int hcol = bc * 64 + wn * 16 + lr;
  const float b_i = bias[hcol];
  const float b_f = bias[2048 + hcol];
  const float b_j = bias[4096 + hcol];
  const float b_o = bias[6144 + hcol];
#pragma unroll
  for (int qm = 0; qm < 2; ++qm)
#pragma unroll
    for (int mr = 0; mr < 4; ++mr)
#pragma unroll
      for (int r = 0; r < 4; ++r) {
        const int row = rb + qm * 128 + wm * 64 + mr * 16 + lk * 4 + r;
        const float gi = acc[qm][mr][0][0][r] + b_i;
        const float gf = acc[qm][mr][0][1][r] + b_f;
        const float gj = acc[qm][mr][1][0][r] + b_j;
        const float go = acc[qm][mr][1][1][r] + b_o;
        const float iv = sigm(gi);
        const float fv = sigm(gf);
        const float jv = tanhf(gj);
        const float ov = sigm(go);
        const size_t idx = (size_t)row * 2048 + hcol;
        const float cp = c_prev[idx];
        const float cv = fv * cp + fminf(1.0f - fv, iv) * jv;
        out_h[idx] = ov * tanhf(cv);
        out_c[idx] = cv;
      }
}

extern "C" void kernel_launch(void* const* d_in, const int* in_sizes, int n_in,
                              void* d_out, int out_size, void* d_ws, size_t ws_size,
                              hipStream_t stream) {
  const float* x      = (const float*)d_in[0];
  const float* h_prev = (const float*)d_in[1];
  const float* c_prev = (const float*)d_in[2];
  const float* w_ih   = (const float*)d_in[3];
  const float* w_hh   = (const float*)d_in[4];
  const float* bias   = (const float*)d_in[5];

  float* out_h = (float*)d_out;
  float* out_c = out_h + (size_t)Bsz * Hd;
  unsigned short* wsb = (unsigned short*)d_ws;

  dim3 cgrid(2048, 4);
  cvt4<<<cgrid, 256, 0, stream>>>(x, h_prev, w_ih, w_hh, wsb);

  lstm_gemm<<<1024, 512, 0, stream>>>(wsb, bias, c_prev, out_h, out_c);
}

// Round 7
// 578.386 us; speedup vs baseline: 1.1065x; 1.0117x over previous
//
#include <hip/hip_runtime.h>

#define DEVI __device__ __forceinline__

typedef __attribute__((ext_vector_type(8))) __bf16 bf16x8;
typedef __attribute__((ext_vector_type(4))) float floatx4;

constexpr int Bsz = 8192;   // batch
constexpr int Hd  = 2048;   // hidden
constexpr int INd = 2048;   // input dim
constexpr int N1  = Bsz * INd;

DEVI unsigned short f2bf_rne(float f) {
  unsigned int u = __float_as_uint(f);
  u += 0x7FFFu + ((u >> 16) & 1u);
  return (unsigned short)(u >> 16);
}

__global__ void cvt4(const float* __restrict__ s0, const float* __restrict__ s1,
                     const float* __restrict__ s2, const float* __restrict__ s3,
                     unsigned short* __restrict__ dst) {
  const float* src = (blockIdx.y == 0) ? s0 : (blockIdx.y == 1) ? s1
                   : (blockIdx.y == 2) ? s2 : s3;
  unsigned short* out = dst + (size_t)blockIdx.y * N1;
  const int nv = N1 / 4;
  for (int i = blockIdx.x * blockDim.x + threadIdx.x; i < nv;
       i += gridDim.x * blockDim.x) {
    float4 v = ((const float4*)src)[i];
    ushort4 o;
    o.x = f2bf_rne(v.x); o.y = f2bf_rne(v.y);
    o.z = f2bf_rne(v.z); o.w = f2bf_rne(v.w);
    ((ushort4*)out)[i] = o;
  }
}

DEVI void gload_lds16(const void* g, void* l) {
  __builtin_amdgcn_global_load_lds(
      (const __attribute__((address_space(1))) void*)g,
      (__attribute__((address_space(3))) void*)l, 16, 0, 0);
}

DEVI float sigm(float x) { return 1.0f / (1.0f + __expf(-x)); }

// 256x256 tile, BK=64, 8 waves (2M x 4N), 16x16x32 MFMA, 0-conflict swizzle,
// 24 ds_read/wave/K-tile (unique minimum), counted vmcnt(4) pipeline.
// R7 change: ONE closing barrier per phase (4/K-tile, was 8), no forced
// lgkmcnt(0)/sched_barrier pinning -> compiler emits counted lgkmcnt and
// waves may skew within a phase, overlapping LDS reads with MFMA.
// WAR safety: each t+2-stage region's last read completes (counted wait
// before its MFMA use) >= one closing barrier before the stage issues.
__global__ __launch_bounds__(512, 2) void lstm_gemm(
    const unsigned short* __restrict__ ws,
    const float* __restrict__ bias,
    const float* __restrict__ c_prev,
    float* __restrict__ out_h,
    float* __restrict__ out_c) {
  __shared__ __align__(16) unsigned short sm[4 * 256 * 64];  // 128 KiB
  char* smc = (char*)sm;

  const unsigned short* xb  = ws;
  const unsigned short* hb  = ws + (size_t)N1;
  const unsigned short* wih = ws + (size_t)2 * N1;
  const unsigned short* whh = ws + (size_t)3 * N1;

  const int tid  = threadIdx.x;
  const int lane = tid & 63;
  const int wid  = tid >> 6;
  const int wm   = wid >> 2, wn = wid & 3;
  const int lr   = lane & 15, lk = lane >> 4;
  const int lr8  = lane >> 3;
  const int swc  = ((lane & 7) ^ lr8) * 8;   // swizzled source chunk (elems)

  // XCD-aware chunked swizzle (FETCH 1.1GB -> 427MB).
  const int wg = blockIdx.x;
  const int x8 = wg & 7;
  const int lc = wg >> 3;
  const int bc = (x8 & 3) * 8 + (lc & 7);             // h-col tile 0..31
  const int rb = ((x8 >> 2) * 16 + (lc >> 3)) * 256;  // batch row base

  // Per-thread stage source offsets (elements), K-tile-independent.
  unsigned int aOff[2][2], bOff[2][2];
#pragma unroll
  for (int h = 0; h < 2; ++h)
#pragma unroll
    for (int j = 0; j < 2; ++j) {
      const int arow = rb + h * 128 + j * 64 + wid * 8 + lr8;
      aOff[h][j] = (unsigned)arow * 2048u + (unsigned)swc;
      const int c  = h * 128 + j * 64 + wid * 8 + lr8;   // block-col index
      const int cf = c >> 4, ce = c & 15;
      const int gate = (cf & 1) | ((cf >> 2) & 2);
      const int hch  = (cf >> 1) & 3;
      const int brow = gate * 2048 + bc * 64 + hch * 16 + ce;
      bOff[h][j] = (unsigned)brow * 2048u + (unsigned)swc;
    }

  floatx4 acc[2][4][2][2];
#pragma unroll
  for (int a = 0; a < 2; ++a)
#pragma unroll
    for (int b = 0; b < 4; ++b)
#pragma unroll
      for (int c = 0; c < 2; ++c)
#pragma unroll
        for (int d = 0; d < 2; ++d)
          acc[a][b][c][d] = (floatx4){0.f, 0.f, 0.f, 0.f};

#define STAGE_A(ts, h) {                                                      \
    const int bs_ = (ts) & 1;                                                 \
    const unsigned short* s_ = (((ts) < 32) ? xb : hb) + (((ts) & 31) * 64);  \
    gload_lds16(s_ + aOff[h][0], smc + bs_ * 32768 + ((h) * 128 + wid * 8) * 128);        \
    gload_lds16(s_ + aOff[h][1], smc + bs_ * 32768 + ((h) * 128 + 64 + wid * 8) * 128); }
#define STAGE_B(ts, h) {                                                      \
    const int bs_ = (ts) & 1;                                                 \
    const unsigned short* s_ = (((ts) < 32) ? wih : whh) + (((ts) & 31) * 64);\
    gload_lds16(s_ + bOff[h][0], smc + 65536 + bs_ * 32768 + ((h) * 128 + wid * 8) * 128);        \
    gload_lds16(s_ + bOff[h][1], smc + 65536 + bs_ * 32768 + ((h) * 128 + 64 + wid * 8) * 128); }

#define LDA(DST, QM)                                                          \
  _Pragma("unroll") for (int mr = 0; mr < 4; ++mr)                            \
    _Pragma("unroll") for (int s = 0; s < 2; ++s) {                           \
      const int row  = (QM) * 128 + wm * 64 + mr * 16 + lr;                   \
      const int phys = (s * 4 + lk) ^ (row & 7);                              \
      DST[mr][s] = *(const bf16x8*)(Ab + row * 128 + phys * 16); }
#define LDB(DST, QN)                                                          \
  _Pragma("unroll") for (int nc = 0; nc < 2; ++nc)                            \
    _Pragma("unroll") for (int s = 0; s < 2; ++s) {                           \
      const int row  = ((QN) * 8 + wn * 2 + nc) * 16 + lr;                    \
      const int phys = (s * 4 + lk) ^ (row & 7);                              \
      DST[nc][s] = *(const bf16x8*)(Bb + row * 128 + phys * 16); }
#define MFMA16(QM, QN, AF, BG)                                                \
  __builtin_amdgcn_s_setprio(1);                                              \
  _Pragma("unroll") for (int mr = 0; mr < 4; ++mr)                            \
    _Pragma("unroll") for (int nc = 0; nc < 2; ++nc)                          \
      _Pragma("unroll") for (int s = 0; s < 2; ++s)                           \
        acc[QM][mr][QN][nc] = __builtin_amdgcn_mfma_f32_16x16x32_bf16(        \
            AF[mr][s], BG[nc][s], acc[QM][mr][QN][nc], 0, 0, 0);              \
  __builtin_amdgcn_s_setprio(0);
#define BAR  asm volatile("s_barrier" ::: "memory")
#define VM4  asm volatile("s_waitcnt vmcnt(4)" ::: "memory")
#define VM0  asm volatile("s_waitcnt vmcnt(0)" ::: "memory")
#define NOP  (void)0

// One K-tile = 4 phases, ring (0,0)(1,0)(1,1)(0,1), ONE closing barrier each.
// Reads: ph1 A0(8)+B0(4), ph2 A1(8), ph3 B1(4), ph4 none (full holds).
// Stage slots: ph1 A(t+1,0); ph2 B(t+1,1), B(t+2,0); ph3 A(t+2,1); ph4 vmcnt.
// WAR: B-beta-h0 last read ph1 -> staged ph2 (after BAR1); A-beta-h1 last
// read ph2 -> staged ph3 (after BAR2). t+1 stages hit the OTHER buffer.
#define KTILE(BETA, S1, S2a, S2b, S3, W4) {                                   \
    const char* Ab = smc + (BETA) * 32768;                                    \
    const char* Bb = smc + 65536 + (BETA) * 32768;                            \
    bf16x8 afA[4][2], afB[4][2], bg0[2][2], bg1[2][2];                        \
    LDA(afA, 0); LDB(bg0, 0); S1;                                             \
    MFMA16(0, 0, afA, bg0); BAR;                                              \
    LDA(afB, 1); S2a; S2b;                                                    \
    MFMA16(1, 0, afB, bg0); BAR;                                              \
    LDB(bg1, 1); S3;                                                          \
    MFMA16(1, 1, afB, bg1); BAR;                                              \
    W4;                                                                       \
    MFMA16(0, 1, afA, bg1); BAR;                                              \
  }

  // Prologue: tile 0 complete (8 gloads) + tile 1's (B0,A1) pair; counted drain.
  STAGE_B(0, 0); STAGE_A(0, 1); STAGE_B(0, 1);
  STAGE_A(0, 0); STAGE_B(1, 0); STAGE_A(1, 1);
  VM4;
  BAR;

  for (int t = 0; t < 62; ++t) {
    KTILE(t & 1, STAGE_A(t + 1, 0), STAGE_B(t + 1, 1),
          STAGE_B(t + 2, 0), STAGE_A(t + 2, 1), VM4);
  }
  KTILE(0, STAGE_A(63, 0), STAGE_B(63, 1), NOP, NOP, VM0);  // t = 62
  KTILE(1, NOP, NOP, NOP, NOP, NOP);                        // t = 63

  // Epilogue: lane-local LSTM (all 4 gates live in-lane).
  const int hcol = bc * 64 + wn * 16 + lr;
  const float b_i = bias[hcol];
  const float b_f = bias[2048 + hcol];
  const float b_j = bias[4096 + hcol];
  const float b_o = bias[6144 + hcol];
#pragma unroll
  for (int qm = 0; qm < 2; ++qm)
#pragma unroll
    for (int mr = 0; mr < 4; ++mr)
#pragma unroll
      for (int r = 0; r < 4; ++r) {
        const int row = rb + qm * 128 + wm * 64 + mr * 16 + lk * 4 + r;
        const float gi = acc[qm][mr][0][0][r] + b_i;
        const float gf = acc[qm][mr][0][1][r] + b_f;
        const float gj = acc[qm][mr][1][0][r] + b_j;
        const float go = acc[qm][mr][1][1][r] + b_o;
        const float iv = sigm(gi);
        const float fv = sigm(gf);
        const float jv = tanhf(gj);
        const float ov = sigm(go);
        const size_t idx = (size_t)row * 2048 + hcol;
        const float cp = c_prev[idx];
        const float cv = fv * cp + fminf(1.0f - fv, iv) * jv;
        out_h[idx] = ov * tanhf(cv);
        out_c[idx] = cv;
      }
}

extern "C" void kernel_launch(void* const* d_in, const int* in_sizes, int n_in,
                              void* d_out, int out_size, void* d_ws, size_t ws_size,
                              hipStream_t stream) {
  const float* x      = (const float*)d_in[0];
  const float* h_prev = (const float*)d_in[1];
  const float* c_prev = (const float*)d_in[2];
  const float* w_ih   = (const float*)d_in[3];
  const float* w_hh   = (const float*)d_in[4];
  const float* bias   = (const float*)d_in[5];

  float* out_h = (float*)d_out;
  float* out_c = out_h + (size_t)Bsz * Hd;
  unsigned short* wsb = (unsigned short*)d_ws;

  dim3 cgrid(2048, 4);
  cvt4<<<cgrid, 256, 0, stream>>>(x, h_prev, w_ih, w_hh, wsb);

  lstm_gemm<<<1024, 512, 0, stream>>>(wsb, bias, c_prev, out_h, out_c);
}